// Round 12
// baseline (764.874 us; speedup 1.0000x reference)
//
#include <hip/hip_runtime.h>

// ShiftWise conv: deep-tile pass1 (16 output rows/thread, 30-row straight-line
// loop, 15-deep rolling lora1 accumulator, all indices static) + bf16 stash;
// pass2 = streaming normalize. lora1(15x3), lora2(3x15), small(3x3), BN'd,
// + residual; ghost channels copied.
// Halo amplification 30/16 = 1.875x (r11: 22/8 = 2.75x) -> ~3x less per-pixel
// overhead. Row validity via clamp+mask (== zero-pad); rb3's 8-row tail via
// uniform scalar guard on folds. No addressable locals, no runtime indices,
// no cross-iteration conditional defs (r5/r8/r10 spill modes excluded).

#define B_    32
#define CIN   256
#define REPN  196
#define HW    56
#define IMG   3136
#define NTOT  (B_ * CIN * IMG)
#define NCONV1   1600   // 25 c-groups x (8 v x 8 c); v = rb*2 + bh, rb 0..3
#define NCONV2R  1400   // fallback pass2 grid (448 thr)
#define NGHOSTBLK 1920
#define STASH_ELEMS (B_ * REPN * IMG)

__device__ __forceinline__ void load_row20(float (&w)[20], const float* __restrict__ in,
                                           int base) {
  int i0 = base;      i0 = i0 < 0 ? 0 : i0;
  int i1 = base + 4;  i1 = i1 < 0 ? 0 : i1;
  int i3 = base + 12; i3 = i3 > (NTOT - 4) ? (NTOT - 4) : i3;
  int i4 = base + 16; i4 = i4 > (NTOT - 4) ? (NTOT - 4) : i4;
  const float4 v0 = *reinterpret_cast<const float4*>(in + i0);
  const float4 v1 = *reinterpret_cast<const float4*>(in + i1);
  const float4 v2 = *reinterpret_cast<const float4*>(in + base + 8);
  const float4 v3 = *reinterpret_cast<const float4*>(in + i3);
  const float4 v4 = *reinterpret_cast<const float4*>(in + i4);
  w[0]=v0.x;  w[1]=v0.y;  w[2]=v0.z;  w[3]=v0.w;
  w[4]=v1.x;  w[5]=v1.y;  w[6]=v1.z;  w[7]=v1.w;
  w[8]=v2.x;  w[9]=v2.y;  w[10]=v2.z; w[11]=v2.w;
  w[12]=v3.x; w[13]=v3.y; w[14]=v3.z; w[15]=v3.w;
  w[16]=v4.x; w[17]=v4.y; w[18]=v4.z; w[19]=v4.w;
}

__device__ __forceinline__ unsigned short pack_bf16(float f) {
  unsigned int u = __float_as_uint(f);
  u = u + 0x7FFFu + ((u >> 16) & 1u);   // RNE
  return (unsigned short)(u >> 16);
}

// ---------- Pass1: 16-row deep tile, 30-row straight-line loop ----------
template <bool STASH>
__launch_bounds__(256)
__global__ void sw_pass1(const float* __restrict__ in, const int* __restrict__ rep_idx,
                         const float* __restrict__ wsum, float* __restrict__ partial,
                         unsigned short* __restrict__ L1, unsigned short* __restrict__ L2,
                         unsigned short* __restrict__ S3) {
  const int bid = blockIdx.x;
  const int tid = threadIdx.x;

  // XCD swizzle: all 8 v-blocks of a channel share bid mod 8 -> same XCD L2.
  const int c = (bid >> 6) * 8 + (bid & 7);
  const int v = (bid >> 3) & 7;         // 0..7
  const int rb = v >> 1, bh = v & 1;    // rb 0..3 (16-row slabs), bh 0..1
  if (c >= REPN) return;
  const int h0 = rb * 16;

  const int bloc = tid / 14;            // 0..18; >=16 inactive
  const int tw = tid - bloc * 14;       // 0..13
  const int w0 = tw * 4;
  const bool act = (bloc < 16);

  float wv[45];  // block-uniform
  #pragma unroll
  for (int j = 0; j < 45; ++j) wv[j] = wsum[c * 45 + j];

  float s1 = 0, q1 = 0, s2 = 0, q2 = 0, s3 = 0, q3 = 0;

  if (act) {
    const int b = bh * 16 + bloc;
    const int src_c = rep_idx[c];
    const int ibase = (b * CIN + src_c) * IMG;
    const int sbase = (b * REPN + c) * IMG;

    const float ma = (tw >= 2) ? 1.f : 0.f;   // window col groups
    const float mb = (tw >= 1) ? 1.f : 0.f;
    const float mc = (tw <= 12) ? 1.f : 0.f;
    const float md = (tw <= 11) ? 1.f : 0.f;

    float acc1[15][4] = {};   // rolling, slot lr%15; freed at fold, reused by lr+15
    float acc2[3][4] = {};
    float acc3[3][4] = {};

    #pragma unroll
    for (int s = 0; s < 30; ++s) {
      const int r0 = h0 - 6 + s;
      const float rm = (r0 >= 0 && r0 < HW) ? 1.f : 0.f;
      const int rr = r0 < 0 ? 0 : (r0 > 55 ? 55 : r0);
      float w20[20];
      load_row20(w20, in, ibase + rr * HW + w0 - 8);

      const float f0 = ma * rm, f1 = mb * rm, f3 = mc * rm, f4 = md * rm;
      float win[20];
      win[0]=w20[0]*f0;   win[1]=w20[1]*f0;   win[2]=w20[2]*f0;   win[3]=w20[3]*f0;
      win[4]=w20[4]*f1;   win[5]=w20[5]*f1;   win[6]=w20[6]*f1;   win[7]=w20[7]*f1;
      win[8]=w20[8]*rm;   win[9]=w20[9]*rm;   win[10]=w20[10]*rm; win[11]=w20[11]*rm;
      win[12]=w20[12]*f3; win[13]=w20[13]*f3; win[14]=w20[14]*f3; win[15]=w20[15]*f3;
      win[16]=w20[16]*f4; win[17]=w20[17]*f4; win[18]=w20[18]*f4; win[19]=w20[19]*f4;

      // lora1 (15x3): output row lr = s - t, active lr in [0,15]
      #pragma unroll
      for (int t = 0; t < 15; ++t) {
        const int lr = s - t;
        if (lr >= 0 && lr <= 15) {
          #pragma unroll
          for (int kw = 0; kw < 3; ++kw) {
            const float wgt = wv[3 * t + kw];
            #pragma unroll
            for (int dw = 0; dw < 4; ++dw)
              acc1[lr % 15][dw] = fmaf(win[dw + kw + 7], wgt, acc1[lr % 15][dw]);
          }
        }
      }
      // lora2 (3x15) + small (3x3): output row lr = s - 5 - kh
      #pragma unroll
      for (int kh = 0; kh < 3; ++kh) {
        const int lr = s - 5 - kh;
        if (lr >= 0 && lr <= 15) {
          #pragma unroll
          for (int T = 0; T < 15; ++T) {
            const float wgt = wv[(T / 3) * 9 + kh * 3 + (T % 3)];
            #pragma unroll
            for (int dw = 0; dw < 4; ++dw)
              acc2[lr % 3][dw] = fmaf(win[dw + T + 2], wgt, acc2[lr % 3][dw]);
          }
          #pragma unroll
          for (int kw = 0; kw < 3; ++kw) {
            const float wgt = wv[18 + kh * 3 + kw];
            #pragma unroll
            for (int dw = 0; dw < 4; ++dw)
              acc3[lr % 3][dw] = fmaf(win[dw + kw + 7], wgt, acc3[lr % 3][dw]);
          }
        }
      }

      // fold1: lora1 row lr = s-14 complete
      if (s >= 14) {
        const int lr = s - 14;
        if (h0 + lr < HW) {       // rb3 tail guard (block-uniform scalar)
          #pragma unroll
          for (int dw = 0; dw < 4; ++dw) {
            const float x = acc1[lr % 15][dw];
            s1 += x; q1 = fmaf(x, x, q1);
          }
          if (STASH) {
            ushort4 t4;
            t4.x = pack_bf16(acc1[lr % 15][0]); t4.y = pack_bf16(acc1[lr % 15][1]);
            t4.z = pack_bf16(acc1[lr % 15][2]); t4.w = pack_bf16(acc1[lr % 15][3]);
            *reinterpret_cast<ushort4*>(L1 + sbase + (h0 + lr) * HW + w0) = t4;
          }
        }
        #pragma unroll
        for (int dw = 0; dw < 4; ++dw) acc1[lr % 15][dw] = 0.f;  // free for lr+15
      }
      // fold2: lora2/small row lr = s-7 complete
      if (s >= 7 && s <= 22) {
        const int lr = s - 7;
        if (h0 + lr < HW) {
          if (STASH) {
            ushort4 t2, t3;
            t2.x = pack_bf16(acc2[lr % 3][0]); t2.y = pack_bf16(acc2[lr % 3][1]);
            t2.z = pack_bf16(acc2[lr % 3][2]); t2.w = pack_bf16(acc2[lr % 3][3]);
            t3.x = pack_bf16(acc3[lr % 3][0]); t3.y = pack_bf16(acc3[lr % 3][1]);
            t3.z = pack_bf16(acc3[lr % 3][2]); t3.w = pack_bf16(acc3[lr % 3][3]);
            *reinterpret_cast<ushort4*>(L2 + sbase + (h0 + lr) * HW + w0) = t2;
            *reinterpret_cast<ushort4*>(S3 + sbase + (h0 + lr) * HW + w0) = t3;
          }
          #pragma unroll
          for (int dw = 0; dw < 4; ++dw) {
            const float v2 = acc2[lr % 3][dw], v3 = acc3[lr % 3][dw];
            s2 += v2; q2 = fmaf(v2, v2, q2);
            s3 += v3; q3 = fmaf(v3, v3, q3);
          }
        }
        #pragma unroll
        for (int dw = 0; dw < 4; ++dw) {
          acc2[lr % 3][dw] = 0.f;
          acc3[lr % 3][dw] = 0.f;
        }
      }
    }
  }

  __shared__ float red[4][6];
  #pragma unroll
  for (int off = 32; off > 0; off >>= 1) {
    s1 += __shfl_down(s1, off); q1 += __shfl_down(q1, off);
    s2 += __shfl_down(s2, off); q2 += __shfl_down(q2, off);
    s3 += __shfl_down(s3, off); q3 += __shfl_down(q3, off);
  }
  const int lane = tid & 63, wid = tid >> 6;
  if (lane == 0) {
    red[wid][0] = s1; red[wid][1] = q1; red[wid][2] = s2;
    red[wid][3] = q2; red[wid][4] = s3; red[wid][5] = q3;
  }
  __syncthreads();
  if (tid < 6)
    partial[(c * 8 + v) * 6 + tid] =
        red[0][tid] + red[1][tid] + red[2][tid] + red[3][tid];
}

// ---------- Fallback pass2: r4-exact recompute (used only if ws too small) ----------
__launch_bounds__(448)
__global__ void sw_pass2r(const float* __restrict__ in, const int* __restrict__ rep_idx,
                          const int* __restrict__ ghost_idx, const float* __restrict__ wsum,
                          const float* __restrict__ stats2, float* __restrict__ out) {
  const int bid = blockIdx.x;
  const int tid = threadIdx.x;

  if (bid >= NCONV2R) {
    const int g = bid - NCONV2R;
    const int j = g >> 5, b = g & 31;
    const int src_c = ghost_idx[j];
    const float4* s = reinterpret_cast<const float4*>(in + (size_t)(b * CIN + src_c) * IMG);
    float4* d = reinterpret_cast<float4*>(out + ((size_t)(b * CIN) + REPN + j) * IMG);
    #pragma unroll 1
    for (int i = tid; i < 784; i += 448) d[i] = s[i];
    return;
  }

  const int c = (bid / 56) * 8 + (bid & 7);
  const int rb = (bid % 56) >> 3;
  if (c >= REPN) return;
  const int h0 = rb * 8;

  const int b = tid / 14;
  const int tw = tid - b * 14;
  const int w0 = tw * 4;
  const int src_c = rep_idx[c];
  const int ibase = (b * CIN + src_c) * IMG;

  float wv[45];
  #pragma unroll
  for (int j = 0; j < 45; ++j) wv[j] = wsum[c * 45 + j];

  const float A1 = stats2[c * 4 + 0], A2 = stats2[c * 4 + 1];
  const float A3 = stats2[c * 4 + 2], K_ = stats2[c * 4 + 3];

  const float ma = (tw >= 2) ? 1.f : 0.f;
  const float mb = (tw >= 1) ? 1.f : 0.f;
  const float mc = (tw <= 12) ? 1.f : 0.f;
  const float md = (tw <= 11) ? 1.f : 0.f;

  float acc1[8][4] = {};
  float acc2[3][4] = {};
  float acc3[3][4] = {};
  float stash[7][4];

  #pragma unroll
  for (int s = 0; s < 22; ++s) {
    const int r = h0 - 6 + s;
    if (r >= 0 && r < HW) {
      float win[20];
      load_row20(win, in, ibase + r * HW + w0 - 8);
      #pragma unroll
      for (int e = 0; e < 4; ++e) win[e] *= ma;
      #pragma unroll
      for (int e = 4; e < 8; ++e) win[e] *= mb;
      #pragma unroll
      for (int e = 12; e < 16; ++e) win[e] *= mc;
      #pragma unroll
      for (int e = 16; e < 20; ++e) win[e] *= md;

      #pragma unroll
      for (int lr = 0; lr < 8; ++lr) {
        const int t = s - lr;
        if (t >= 0 && t < 15) {
          #pragma unroll
          for (int kw = 0; kw < 3; ++kw) {
            const float wgt = wv[3 * t + kw];
            #pragma unroll
            for (int dw = 0; dw < 4; ++dw)
              acc1[lr][dw] = fmaf(win[dw + kw + 7], wgt, acc1[lr][dw]);
          }
        }
      }
      #pragma unroll
      for (int lr = 0; lr < 8; ++lr) {
        const int kh = s - lr - 5;
        if (kh >= 0 && kh < 3) {
          #pragma unroll
          for (int T = 0; T < 15; ++T) {
            const float wgt = wv[(T / 3) * 9 + kh * 3 + (T % 3)];
            #pragma unroll
            for (int dw = 0; dw < 4; ++dw)
              acc2[lr % 3][dw] = fmaf(win[dw + T + 2], wgt, acc2[lr % 3][dw]);
          }
          #pragma unroll
          for (int kw = 0; kw < 3; ++kw) {
            const float wgt = wv[18 + kh * 3 + kw];
            #pragma unroll
            for (int dw = 0; dw < 4; ++dw)
              acc3[lr % 3][dw] = fmaf(win[dw + kw + 7], wgt, acc3[lr % 3][dw]);
          }
        }
      }
    }

    if (s >= 14) {
      const int lr = s - 14;
      const int hh = h0 + lr;
      const float4 xv = *reinterpret_cast<const float4*>(in + ibase + hh * HW + w0);
      float4 o;
      o.x = fmaf(A1, acc1[lr][0], stash[lr % 7][0] + K_ + xv.x);
      o.y = fmaf(A1, acc1[lr][1], stash[lr % 7][1] + K_ + xv.y);
      o.z = fmaf(A1, acc1[lr][2], stash[lr % 7][2] + K_ + xv.z);
      o.w = fmaf(A1, acc1[lr][3], stash[lr % 7][3] + K_ + xv.w);
      *reinterpret_cast<float4*>(out + (size_t)(b * CIN + c) * IMG + hh * HW + w0) = o;
    }
    if (s >= 7 && s <= 14) {
      const int lr = s - 7;
      #pragma unroll
      for (int dw = 0; dw < 4; ++dw) {
        stash[lr % 7][dw] = fmaf(A2, acc2[lr % 3][dw], A3 * acc3[lr % 3][dw]);
        acc2[lr % 3][dw] = 0.f;
        acc3[lr % 3][dw] = 0.f;
      }
    }
  }
}

// ---------- Fast pass2: streaming normalize from bf16 stash ----------
__launch_bounds__(256)
__global__ void sw_norm(const float* __restrict__ in, const int* __restrict__ rep_idx,
                        const int* __restrict__ ghost_idx, const float* __restrict__ stats2,
                        const unsigned short* __restrict__ L1,
                        const unsigned short* __restrict__ L2,
                        const unsigned short* __restrict__ S3,
                        float* __restrict__ out) {
  const int bid = blockIdx.x;
  const int tid = threadIdx.x;
  if (bid >= 6272) {  // ghost copy
    const int g = bid - 6272;
    const int j = g >> 5, b = g & 31;
    const int src_c = ghost_idx[j];
    const float4* s = reinterpret_cast<const float4*>(in + (size_t)(b * CIN + src_c) * IMG);
    float4* d = reinterpret_cast<float4*>(out + ((size_t)(b * CIN) + REPN + j) * IMG);
    #pragma unroll 1
    for (int i = tid; i < 784; i += 256) d[i] = s[i];
    return;
  }
  const int c = bid >> 5, b = bid & 31;
  const float A1 = stats2[c * 4 + 0], A2 = stats2[c * 4 + 1];
  const float A3 = stats2[c * 4 + 2], K_ = stats2[c * 4 + 3];
  const int xb4 = (b * CIN + rep_idx[c]) * IMG / 4;
  const int ob4 = (b * CIN + c) * IMG / 4;
  const int sb4 = (b * REPN + c) * IMG / 4;
  const float4* xp = reinterpret_cast<const float4*>(in) + xb4;
  float4* op = reinterpret_cast<float4*>(out) + ob4;
  const ushort4* l1p = reinterpret_cast<const ushort4*>(L1) + sb4;
  const ushort4* l2p = reinterpret_cast<const ushort4*>(L2) + sb4;
  const ushort4* s3p = reinterpret_cast<const ushort4*>(S3) + sb4;
  #pragma unroll 1
  for (int g = tid; g < 784; g += 256) {
    const float4 x = xp[g];
    const ushort4 a = l1p[g], d2 = l2p[g], d3 = s3p[g];
    float4 y;
    y.x = fmaf(A1, __uint_as_float((unsigned)a.x << 16),
          fmaf(A2, __uint_as_float((unsigned)d2.x << 16),
          fmaf(A3, __uint_as_float((unsigned)d3.x << 16), K_ + x.x)));
    y.y = fmaf(A1, __uint_as_float((unsigned)a.y << 16),
          fmaf(A2, __uint_as_float((unsigned)d2.y << 16),
          fmaf(A3, __uint_as_float((unsigned)d3.y << 16), K_ + x.y)));
    y.z = fmaf(A1, __uint_as_float((unsigned)a.z << 16),
          fmaf(A2, __uint_as_float((unsigned)d2.z << 16),
          fmaf(A3, __uint_as_float((unsigned)d3.z << 16), K_ + x.z)));
    y.w = fmaf(A1, __uint_as_float((unsigned)a.w << 16),
          fmaf(A2, __uint_as_float((unsigned)d2.w << 16),
          fmaf(A3, __uint_as_float((unsigned)d3.w << 16), K_ + x.w)));
    op[g] = y;
  }
}

extern "C" __global__ void sw_prep(const float* __restrict__ w1, const float* __restrict__ w2,
                                   float* __restrict__ wsum) {
  int i = blockIdx.x * 256 + threadIdx.x;
  if (i < 8820) wsum[i] = w1[i] + w2[i];
}

extern "C" __global__ void sw_reduce(
    const float* __restrict__ partial,
    const float* __restrict__ g1, const float* __restrict__ b1,
    const float* __restrict__ g2, const float* __restrict__ b2,
    const float* __restrict__ g3, const float* __restrict__ b3,
    float* __restrict__ stats2) {
  const int c = blockIdx.x;
  const int tid = threadIdx.x;
  __shared__ float sm[6];
  if (tid < 6) {
    float s = 0;
    #pragma unroll
    for (int v = 0; v < 8; ++v) s += partial[(c * 8 + v) * 6 + tid];
    sm[tid] = s;
  }
  __syncthreads();
  if (tid == 0) {
    const float N = 100352.f;
    float m1 = sm[0] / N, v1 = sm[1] / N - m1 * m1;
    float m2 = sm[2] / N, v2 = sm[3] / N - m2 * m2;
    float m3 = sm[4] / N, v3 = sm[5] / N - m3 * m3;
    float A1 = g1[c] * rsqrtf(v1 + 1e-5f);
    float A2 = g2[c] * rsqrtf(v2 + 1e-5f);
    float A3 = g3[c] * rsqrtf(v3 + 1e-5f);
    float K = b1[c] + b2[c] + b3[c] - m1 * A1 - m2 * A2 - m3 * A3;
    stats2[c * 4 + 0] = A1; stats2[c * 4 + 1] = A2;
    stats2[c * 4 + 2] = A3; stats2[c * 4 + 3] = K;
  }
}

extern "C" void kernel_launch(void* const* d_in, const int* in_sizes, int n_in,
                              void* d_out, int out_size, void* d_ws, size_t ws_size,
                              hipStream_t stream) {
  const float* in  = (const float*)d_in[0];
  const float* w1  = (const float*)d_in[1];
  const float* w2  = (const float*)d_in[2];
  const float* g1  = (const float*)d_in[3];
  const float* b1  = (const float*)d_in[4];
  const float* g2  = (const float*)d_in[5];
  const float* b2  = (const float*)d_in[6];
  const float* g3  = (const float*)d_in[7];
  const float* b3  = (const float*)d_in[8];
  const int* ghost_idx = (const int*)d_in[9];
  const int* rep_idx   = (const int*)d_in[10];
  float* out = (float*)d_out;
  float* ws  = (float*)d_ws;

  float* wsum    = ws;          // 8820 floats
  float* stats2  = ws + 8832;   // 784 floats
  float* partial = ws + 9728;   // 196*8*6 = 9408 floats
  unsigned short* L1 = reinterpret_cast<unsigned short*>((char*)d_ws + (1u << 18));
  unsigned short* L2 = L1 + STASH_ELEMS;
  unsigned short* S3 = L2 + STASH_ELEMS;
  const size_t need = (1u << 18) + 3ull * STASH_ELEMS * sizeof(unsigned short);

  sw_prep<<<35, 256, 0, stream>>>(w1, w2, wsum);
  if (ws_size >= need) {
    sw_pass1<true><<<NCONV1, 256, 0, stream>>>(in, rep_idx, wsum, partial, L1, L2, S3);
    sw_reduce<<<196, 64, 0, stream>>>(partial, g1, b1, g2, b2, g3, b3, stats2);
    sw_norm<<<6272 + NGHOSTBLK, 256, 0, stream>>>(in, rep_idx, ghost_idx, stats2,
                                                  L1, L2, S3, out);
  } else {
    sw_pass1<false><<<NCONV1, 256, 0, stream>>>(in, rep_idx, wsum, partial, L1, L2, S3);
    sw_reduce<<<196, 64, 0, stream>>>(partial, g1, b1, g2, b2, g3, b3, stats2);
    sw_pass2r<<<NCONV2R + NGHOSTBLK, 448, 0, stream>>>(in, rep_idx, ghost_idx, wsum,
                                                       stats2, out);
  }
}

// Round 13
// 210.406 us; speedup vs baseline: 3.6352x; 3.6352x over previous
//
#include <hip/hip_runtime.h>

// ShiftWise conv: r4-proven guarded conv core in 64-thread (1-wave) blocks
// (no LDS, no syncthreads, wave-shuffle stats) + bf16 stash + streaming norm.
// lora1(15x3), lora2(3x15), small(3x3) per rep channel, BN'd with batch
// stats, + rep_x residual; ghost channels copied through.
// Theory: conv kernels have shown ~6 waves/CU occupancy regardless of VGPR ->
// workgroup-granularity limited. 1-wave workgroups -> ~16 waves/CU -> row-load
// latency (the 60% stall at r4/r9) overlaps across waves.
// Pass1: per-(c,rb,bg) sum/sumsq partials + bf16 (RNE) conv outputs to d_ws.
// Reduce: fold stats into (A1,A2,A3,K).
// sw_norm: y = A1*l1 + A2*l2 + A3*s + K + x (+ghost copy).
// Fallback (ws too small): r4-exact recompute pass2 (448 thr).

#define B_    32
#define CIN   256
#define REPN  196
#define HW    56
#define IMG   3136
#define NTOT  (B_ * CIN * IMG)
#define NCONV1   11200  // 25 c-groups x 8 c x (7 rb x 8 bg)
#define NCONV2R  1400   // fallback pass2 grid (448 thr)
#define NGHOSTBLK 1920
#define STASH_ELEMS (B_ * REPN * IMG)

__device__ __forceinline__ void load_row20(float (&w)[20], const float* __restrict__ in,
                                           int base) {
  int i0 = base;      i0 = i0 < 0 ? 0 : i0;
  int i1 = base + 4;  i1 = i1 < 0 ? 0 : i1;
  int i3 = base + 12; i3 = i3 > (NTOT - 4) ? (NTOT - 4) : i3;
  int i4 = base + 16; i4 = i4 > (NTOT - 4) ? (NTOT - 4) : i4;
  const float4 v0 = *reinterpret_cast<const float4*>(in + i0);
  const float4 v1 = *reinterpret_cast<const float4*>(in + i1);
  const float4 v2 = *reinterpret_cast<const float4*>(in + base + 8);
  const float4 v3 = *reinterpret_cast<const float4*>(in + i3);
  const float4 v4 = *reinterpret_cast<const float4*>(in + i4);
  w[0]=v0.x;  w[1]=v0.y;  w[2]=v0.z;  w[3]=v0.w;
  w[4]=v1.x;  w[5]=v1.y;  w[6]=v1.z;  w[7]=v1.w;
  w[8]=v2.x;  w[9]=v2.y;  w[10]=v2.z; w[11]=v2.w;
  w[12]=v3.x; w[13]=v3.y; w[14]=v3.z; w[15]=v3.w;
  w[16]=v4.x; w[17]=v4.y; w[18]=v4.z; w[19]=v4.w;
}

__device__ __forceinline__ unsigned short pack_bf16(float f) {
  unsigned int u = __float_as_uint(f);
  u = u + 0x7FFFu + ((u >> 16) & 1u);   // RNE
  return (unsigned short)(u >> 16);
}

// ---------- Pass1: 1-wave blocks, r4 guarded conv core + stats + stash ----------
template <bool STASH>
__launch_bounds__(64)
__global__ void sw_pass1(const float* __restrict__ in, const int* __restrict__ rep_idx,
                         const float* __restrict__ wsum, float* __restrict__ partial,
                         unsigned short* __restrict__ L1, unsigned short* __restrict__ L2,
                         unsigned short* __restrict__ S3) {
  const int bid = blockIdx.x;
  const int lane = threadIdx.x;        // 0..63

  // XCD swizzle: all 56 (rb,bg)-blocks of channel c share bid mod 8.
  const int c = (bid / 448) * 8 + (bid & 7);
  const int v = (bid % 448) >> 3;      // 0..55
  const int rb = v >> 3, bg = v & 7;   // rb 0..6, bg 0..7
  if (c >= REPN) return;
  const int h0 = rb * 8;

  const int bloc = lane / 14;          // 0..4; ==4 -> idle (lanes 56..63)
  const int tw = lane - bloc * 14;     // 0..13
  const int w0 = tw * 4;
  const bool act = (bloc < 4);

  float wv[45];  // block-uniform
  #pragma unroll
  for (int j = 0; j < 45; ++j) wv[j] = wsum[c * 45 + j];

  float s1 = 0, q1 = 0, s2 = 0, q2 = 0, s3 = 0, q3 = 0;

  if (act) {
    const int b = bg * 4 + bloc;
    const int src_c = rep_idx[c];
    const int ibase = (b * CIN + src_c) * IMG;
    const int sbase = (b * REPN + c) * IMG;

    const float ma = (tw >= 2) ? 1.f : 0.f;   // window col masks
    const float mb = (tw >= 1) ? 1.f : 0.f;
    const float mc = (tw <= 12) ? 1.f : 0.f;
    const float md = (tw <= 11) ? 1.f : 0.f;

    const int s_lo = (rb == 0) ? 6 : 0;       // r = h0-6+s in [0,56)
    const int s_hi = (rb == 6) ? 13 : 21;

    float acc1[8][4] = {};
    float acc2[3][4] = {};
    float acc3[3][4] = {};

    #pragma unroll
    for (int s = 0; s < 22; ++s) {
      if (s >= s_lo && s <= s_hi) {
        const int r = h0 - 6 + s;
        float win[20];
        load_row20(win, in, ibase + r * HW + w0 - 8);
        #pragma unroll
        for (int e = 0; e < 4; ++e) win[e] *= ma;
        #pragma unroll
        for (int e = 4; e < 8; ++e) win[e] *= mb;
        #pragma unroll
        for (int e = 12; e < 16; ++e) win[e] *= mc;
        #pragma unroll
        for (int e = 16; e < 20; ++e) win[e] *= md;

        // lora1 (15x3): vertical tap t = s - lr; x col -> e = dw+kw+7
        #pragma unroll
        for (int lr = 0; lr < 8; ++lr) {
          const int t = s - lr;
          if (t >= 0 && t < 15) {
            #pragma unroll
            for (int kw = 0; kw < 3; ++kw) {
              const float wgt = wv[3 * t + kw];
              #pragma unroll
              for (int dw = 0; dw < 4; ++dw)
                acc1[lr][dw] = fmaf(win[dw + kw + 7], wgt, acc1[lr][dw]);
            }
          }
        }
        // lora2 (3x15) + small (3x3): kh = s - lr - 5
        #pragma unroll
        for (int lr = 0; lr < 8; ++lr) {
          const int kh = s - lr - 5;
          if (kh >= 0 && kh < 3) {
            #pragma unroll
            for (int T = 0; T < 15; ++T) {      // horiz tap -> e = dw+T+2
              const float wgt = wv[(T / 3) * 9 + kh * 3 + (T % 3)];
              #pragma unroll
              for (int dw = 0; dw < 4; ++dw)
                acc2[lr % 3][dw] = fmaf(win[dw + T + 2], wgt, acc2[lr % 3][dw]);
            }
            #pragma unroll
            for (int kw = 0; kw < 3; ++kw) {
              const float wgt = wv[18 + kh * 3 + kw];
              #pragma unroll
              for (int dw = 0; dw < 4; ++dw)
                acc3[lr % 3][dw] = fmaf(win[dw + kw + 7], wgt, acc3[lr % 3][dw]);
            }
          }
        }
      }

      if (s >= 14) {               // fold1: lora1 row lr complete
        const int lr = s - 14;
        #pragma unroll
        for (int dw = 0; dw < 4; ++dw) {
          const float x = acc1[lr][dw];
          s1 += x; q1 = fmaf(x, x, q1);
        }
        if (STASH) {
          ushort4 t4;
          t4.x = pack_bf16(acc1[lr][0]); t4.y = pack_bf16(acc1[lr][1]);
          t4.z = pack_bf16(acc1[lr][2]); t4.w = pack_bf16(acc1[lr][3]);
          *reinterpret_cast<ushort4*>(L1 + sbase + (h0 + lr) * HW + w0) = t4;
        }
      }
      if (s >= 7 && s <= 14) {     // fold2: lora2/small row lr complete
        const int lr = s - 7;
        if (STASH) {
          ushort4 t2, t3;
          t2.x = pack_bf16(acc2[lr % 3][0]); t2.y = pack_bf16(acc2[lr % 3][1]);
          t2.z = pack_bf16(acc2[lr % 3][2]); t2.w = pack_bf16(acc2[lr % 3][3]);
          t3.x = pack_bf16(acc3[lr % 3][0]); t3.y = pack_bf16(acc3[lr % 3][1]);
          t3.z = pack_bf16(acc3[lr % 3][2]); t3.w = pack_bf16(acc3[lr % 3][3]);
          *reinterpret_cast<ushort4*>(L2 + sbase + (h0 + lr) * HW + w0) = t2;
          *reinterpret_cast<ushort4*>(S3 + sbase + (h0 + lr) * HW + w0) = t3;
        }
        #pragma unroll
        for (int dw = 0; dw < 4; ++dw) {
          const float v2 = acc2[lr % 3][dw], v3 = acc3[lr % 3][dw];
          s2 += v2; q2 = fmaf(v2, v2, q2);
          s3 += v3; q3 = fmaf(v3, v3, q3);
          acc2[lr % 3][dw] = 0.f;
          acc3[lr % 3][dw] = 0.f;
        }
      }
    }
  }

  // full-wave shuffle reduce (idle lanes contribute zeros); no LDS, no barrier
  #pragma unroll
  for (int off = 32; off > 0; off >>= 1) {
    s1 += __shfl_down(s1, off); q1 += __shfl_down(q1, off);
    s2 += __shfl_down(s2, off); q2 += __shfl_down(q2, off);
    s3 += __shfl_down(s3, off); q3 += __shfl_down(q3, off);
  }
  if (lane == 0) {
    float* p = partial + (size_t)(c * 56 + rb * 8 + bg) * 6;
    p[0] = s1; p[1] = q1; p[2] = s2; p[3] = q2; p[4] = s3; p[5] = q3;
  }
}

// ---------- Fallback pass2: r4-exact recompute (only if ws too small) ----------
__launch_bounds__(448)
__global__ void sw_pass2r(const float* __restrict__ in, const int* __restrict__ rep_idx,
                          const int* __restrict__ ghost_idx, const float* __restrict__ wsum,
                          const float* __restrict__ stats2, float* __restrict__ out) {
  const int bid = blockIdx.x;
  const int tid = threadIdx.x;

  if (bid >= NCONV2R) {
    const int g = bid - NCONV2R;
    const int j = g >> 5, b = g & 31;
    const int src_c = ghost_idx[j];
    const float4* s = reinterpret_cast<const float4*>(in + (size_t)(b * CIN + src_c) * IMG);
    float4* d = reinterpret_cast<float4*>(out + ((size_t)(b * CIN) + REPN + j) * IMG);
    #pragma unroll 1
    for (int i = tid; i < 784; i += 448) d[i] = s[i];
    return;
  }

  const int c = (bid / 56) * 8 + (bid & 7);
  const int rb = (bid % 56) >> 3;
  if (c >= REPN) return;
  const int h0 = rb * 8;

  const int b = tid / 14;
  const int tw = tid - b * 14;
  const int w0 = tw * 4;
  const int src_c = rep_idx[c];
  const int ibase = (b * CIN + src_c) * IMG;

  float wv[45];
  #pragma unroll
  for (int j = 0; j < 45; ++j) wv[j] = wsum[c * 45 + j];

  const float A1 = stats2[c * 4 + 0], A2 = stats2[c * 4 + 1];
  const float A3 = stats2[c * 4 + 2], K_ = stats2[c * 4 + 3];

  const float ma = (tw >= 2) ? 1.f : 0.f;
  const float mb = (tw >= 1) ? 1.f : 0.f;
  const float mc = (tw <= 12) ? 1.f : 0.f;
  const float md = (tw <= 11) ? 1.f : 0.f;

  float acc1[8][4] = {};
  float acc2[3][4] = {};
  float acc3[3][4] = {};
  float stash[7][4];

  #pragma unroll
  for (int s = 0; s < 22; ++s) {
    const int r = h0 - 6 + s;
    if (r >= 0 && r < HW) {
      float win[20];
      load_row20(win, in, ibase + r * HW + w0 - 8);
      #pragma unroll
      for (int e = 0; e < 4; ++e) win[e] *= ma;
      #pragma unroll
      for (int e = 4; e < 8; ++e) win[e] *= mb;
      #pragma unroll
      for (int e = 12; e < 16; ++e) win[e] *= mc;
      #pragma unroll
      for (int e = 16; e < 20; ++e) win[e] *= md;

      #pragma unroll
      for (int lr = 0; lr < 8; ++lr) {
        const int t = s - lr;
        if (t >= 0 && t < 15) {
          #pragma unroll
          for (int kw = 0; kw < 3; ++kw) {
            const float wgt = wv[3 * t + kw];
            #pragma unroll
            for (int dw = 0; dw < 4; ++dw)
              acc1[lr][dw] = fmaf(win[dw + kw + 7], wgt, acc1[lr][dw]);
          }
        }
      }
      #pragma unroll
      for (int lr = 0; lr < 8; ++lr) {
        const int kh = s - lr - 5;
        if (kh >= 0 && kh < 3) {
          #pragma unroll
          for (int T = 0; T < 15; ++T) {
            const float wgt = wv[(T / 3) * 9 + kh * 3 + (T % 3)];
            #pragma unroll
            for (int dw = 0; dw < 4; ++dw)
              acc2[lr % 3][dw] = fmaf(win[dw + T + 2], wgt, acc2[lr % 3][dw]);
          }
          #pragma unroll
          for (int kw = 0; kw < 3; ++kw) {
            const float wgt = wv[18 + kh * 3 + kw];
            #pragma unroll
            for (int dw = 0; dw < 4; ++dw)
              acc3[lr % 3][dw] = fmaf(win[dw + kw + 7], wgt, acc3[lr % 3][dw]);
          }
        }
      }
    }

    if (s >= 14) {
      const int lr = s - 14;
      const int hh = h0 + lr;
      const float4 xv = *reinterpret_cast<const float4*>(in + ibase + hh * HW + w0);
      float4 o;
      o.x = fmaf(A1, acc1[lr][0], stash[lr % 7][0] + K_ + xv.x);
      o.y = fmaf(A1, acc1[lr][1], stash[lr % 7][1] + K_ + xv.y);
      o.z = fmaf(A1, acc1[lr][2], stash[lr % 7][2] + K_ + xv.z);
      o.w = fmaf(A1, acc1[lr][3], stash[lr % 7][3] + K_ + xv.w);
      *reinterpret_cast<float4*>(out + (size_t)(b * CIN + c) * IMG + hh * HW + w0) = o;
    }
    if (s >= 7 && s <= 14) {
      const int lr = s - 7;
      #pragma unroll
      for (int dw = 0; dw < 4; ++dw) {
        stash[lr % 7][dw] = fmaf(A2, acc2[lr % 3][dw], A3 * acc3[lr % 3][dw]);
        acc2[lr % 3][dw] = 0.f;
        acc3[lr % 3][dw] = 0.f;
      }
    }
  }
}

// ---------- Fast pass2: streaming normalize from bf16 stash ----------
__launch_bounds__(256)
__global__ void sw_norm(const float* __restrict__ in, const int* __restrict__ rep_idx,
                        const int* __restrict__ ghost_idx, const float* __restrict__ stats2,
                        const unsigned short* __restrict__ L1,
                        const unsigned short* __restrict__ L2,
                        const unsigned short* __restrict__ S3,
                        float* __restrict__ out) {
  const int bid = blockIdx.x;
  const int tid = threadIdx.x;
  if (bid >= 6272) {  // ghost copy
    const int g = bid - 6272;
    const int j = g >> 5, b = g & 31;
    const int src_c = ghost_idx[j];
    const float4* s = reinterpret_cast<const float4*>(in + (size_t)(b * CIN + src_c) * IMG);
    float4* d = reinterpret_cast<float4*>(out + ((size_t)(b * CIN) + REPN + j) * IMG);
    #pragma unroll 1
    for (int i = tid; i < 784; i += 256) d[i] = s[i];
    return;
  }
  const int c = bid >> 5, b = bid & 31;
  const float A1 = stats2[c * 4 + 0], A2 = stats2[c * 4 + 1];
  const float A3 = stats2[c * 4 + 2], K_ = stats2[c * 4 + 3];
  const int xb4 = (b * CIN + rep_idx[c]) * IMG / 4;
  const int ob4 = (b * CIN + c) * IMG / 4;
  const int sb4 = (b * REPN + c) * IMG / 4;
  const float4* xp = reinterpret_cast<const float4*>(in) + xb4;
  float4* op = reinterpret_cast<float4*>(out) + ob4;
  const ushort4* l1p = reinterpret_cast<const ushort4*>(L1) + sb4;
  const ushort4* l2p = reinterpret_cast<const ushort4*>(L2) + sb4;
  const ushort4* s3p = reinterpret_cast<const ushort4*>(S3) + sb4;
  #pragma unroll 1
  for (int g = tid; g < 784; g += 256) {
    const float4 x = xp[g];
    const ushort4 a = l1p[g], d2 = l2p[g], d3 = s3p[g];
    float4 y;
    y.x = fmaf(A1, __uint_as_float((unsigned)a.x << 16),
          fmaf(A2, __uint_as_float((unsigned)d2.x << 16),
          fmaf(A3, __uint_as_float((unsigned)d3.x << 16), K_ + x.x)));
    y.y = fmaf(A1, __uint_as_float((unsigned)a.y << 16),
          fmaf(A2, __uint_as_float((unsigned)d2.y << 16),
          fmaf(A3, __uint_as_float((unsigned)d3.y << 16), K_ + x.y)));
    y.z = fmaf(A1, __uint_as_float((unsigned)a.z << 16),
          fmaf(A2, __uint_as_float((unsigned)d2.z << 16),
          fmaf(A3, __uint_as_float((unsigned)d3.z << 16), K_ + x.z)));
    y.w = fmaf(A1, __uint_as_float((unsigned)a.w << 16),
          fmaf(A2, __uint_as_float((unsigned)d2.w << 16),
          fmaf(A3, __uint_as_float((unsigned)d3.w << 16), K_ + x.w)));
    op[g] = y;
  }
}

extern "C" __global__ void sw_prep(const float* __restrict__ w1, const float* __restrict__ w2,
                                   float* __restrict__ wsum) {
  int i = blockIdx.x * 256 + threadIdx.x;
  if (i < 8820) wsum[i] = w1[i] + w2[i];
}

extern "C" __global__ void sw_reduce(
    const float* __restrict__ partial,
    const float* __restrict__ g1, const float* __restrict__ b1,
    const float* __restrict__ g2, const float* __restrict__ b2,
    const float* __restrict__ g3, const float* __restrict__ b3,
    float* __restrict__ stats2) {
  const int c = blockIdx.x;
  const int tid = threadIdx.x;
  __shared__ float sm[6];
  if (tid < 6) {
    float s = 0;
    #pragma unroll 1
    for (int u = 0; u < 56; ++u) s += partial[(size_t)(c * 56 + u) * 6 + tid];
    sm[tid] = s;
  }
  __syncthreads();
  if (tid == 0) {
    const float N = 100352.f;
    float m1 = sm[0] / N, v1 = sm[1] / N - m1 * m1;
    float m2 = sm[2] / N, v2 = sm[3] / N - m2 * m2;
    float m3 = sm[4] / N, v3 = sm[5] / N - m3 * m3;
    float A1 = g1[c] * rsqrtf(v1 + 1e-5f);
    float A2 = g2[c] * rsqrtf(v2 + 1e-5f);
    float A3 = g3[c] * rsqrtf(v3 + 1e-5f);
    float K = b1[c] + b2[c] + b3[c] - m1 * A1 - m2 * A2 - m3 * A3;
    stats2[c * 4 + 0] = A1; stats2[c * 4 + 1] = A2;
    stats2[c * 4 + 2] = A3; stats2[c * 4 + 3] = K;
  }
}

extern "C" void kernel_launch(void* const* d_in, const int* in_sizes, int n_in,
                              void* d_out, int out_size, void* d_ws, size_t ws_size,
                              hipStream_t stream) {
  const float* in  = (const float*)d_in[0];
  const float* w1  = (const float*)d_in[1];
  const float* w2  = (const float*)d_in[2];
  const float* g1  = (const float*)d_in[3];
  const float* b1  = (const float*)d_in[4];
  const float* g2  = (const float*)d_in[5];
  const float* b2  = (const float*)d_in[6];
  const float* g3  = (const float*)d_in[7];
  const float* b3  = (const float*)d_in[8];
  const int* ghost_idx = (const int*)d_in[9];
  const int* rep_idx   = (const int*)d_in[10];
  float* out = (float*)d_out;
  float* ws  = (float*)d_ws;

  float* wsum    = ws;          // 8820 floats
  float* stats2  = ws + 8832;   // 784 floats
  float* partial = ws + 9728;   // 196*56*6 = 65856 floats (fits below 512 KB)
  unsigned short* L1 = reinterpret_cast<unsigned short*>((char*)d_ws + (1u << 19));
  unsigned short* L2 = L1 + STASH_ELEMS;
  unsigned short* S3 = L2 + STASH_ELEMS;
  const size_t need = (1u << 19) + 3ull * STASH_ELEMS * sizeof(unsigned short);

  sw_prep<<<35, 256, 0, stream>>>(w1, w2, wsum);
  if (ws_size >= need) {
    sw_pass1<true><<<NCONV1, 64, 0, stream>>>(in, rep_idx, wsum, partial, L1, L2, S3);
    sw_reduce<<<196, 64, 0, stream>>>(partial, g1, b1, g2, b2, g3, b3, stats2);
    sw_norm<<<6272 + NGHOSTBLK, 256, 0, stream>>>(in, rep_idx, ghost_idx, stats2,
                                                  L1, L2, S3, out);
  } else {
    sw_pass1<false><<<NCONV1, 64, 0, stream>>>(in, rep_idx, wsum, partial, L1, L2, S3);
    sw_reduce<<<196, 64, 0, stream>>>(partial, g1, b1, g2, b2, g3, b3, stats2);
    sw_pass2r<<<NCONV2R + NGHOSTBLK, 448, 0, stream>>>(in, rep_idx, ghost_idx, wsum,
                                                       stats2, out);
  }
}

// Round 14
// 195.718 us; speedup vs baseline: 3.9080x; 1.0750x over previous
//
#include <hip/hip_runtime.h>

// ShiftWise conv: dual-batch interleaved pass1 (two independent dep-chains
// per thread: batches b and b+16; 10 unconditional loads per guarded row ->
// 2x compute per vmcnt wait) + bf16 stash + streaming normalize.
// lora1(15x3), lora2(3x15), small(3x3) per rep channel, BN'd with batch
// stats, + rep_x residual; ghost channels copied through.
// Core is r4/r9's proven-clean guarded structure (in-iteration conditional
// defs only, static indices, no VGPR cap) -- just doubled in-iteration state.
// Pass1: per-(c,rb) sum/sumsq partials + bf16 (RNE) conv outputs to d_ws.
// Reduce: fold stats into (A1,A2,A3,K).
// sw_norm: y = A1*l1 + A2*l2 + A3*s + K + x (+ghost copy).
// Fallback (ws too small): r4-exact recompute pass2 (448 thr).

#define B_    32
#define CIN   256
#define REPN  196
#define HW    56
#define IMG   3136
#define NTOT  (B_ * CIN * IMG)
#define NCONV1   1400   // 25 c-groups of 56 = (8 c x 7 rb); 256 thr, 2 batches/thr
#define NCONV2R  1400   // fallback pass2 grid (448 thr)
#define NGHOSTBLK 1920
#define STASH_ELEMS (B_ * REPN * IMG)

__device__ __forceinline__ void load_row20(float (&w)[20], const float* __restrict__ in,
                                           int base) {
  int i0 = base;      i0 = i0 < 0 ? 0 : i0;
  int i1 = base + 4;  i1 = i1 < 0 ? 0 : i1;
  int i3 = base + 12; i3 = i3 > (NTOT - 4) ? (NTOT - 4) : i3;
  int i4 = base + 16; i4 = i4 > (NTOT - 4) ? (NTOT - 4) : i4;
  const float4 v0 = *reinterpret_cast<const float4*>(in + i0);
  const float4 v1 = *reinterpret_cast<const float4*>(in + i1);
  const float4 v2 = *reinterpret_cast<const float4*>(in + base + 8);
  const float4 v3 = *reinterpret_cast<const float4*>(in + i3);
  const float4 v4 = *reinterpret_cast<const float4*>(in + i4);
  w[0]=v0.x;  w[1]=v0.y;  w[2]=v0.z;  w[3]=v0.w;
  w[4]=v1.x;  w[5]=v1.y;  w[6]=v1.z;  w[7]=v1.w;
  w[8]=v2.x;  w[9]=v2.y;  w[10]=v2.z; w[11]=v2.w;
  w[12]=v3.x; w[13]=v3.y; w[14]=v3.z; w[15]=v3.w;
  w[16]=v4.x; w[17]=v4.y; w[18]=v4.z; w[19]=v4.w;
}

__device__ __forceinline__ unsigned short pack_bf16(float f) {
  unsigned int u = __float_as_uint(f);
  u = u + 0x7FFFu + ((u >> 16) & 1u);   // RNE
  return (unsigned short)(u >> 16);
}

// ---------- Pass1: dual-batch guarded conv + stats + bf16 stash ----------
template <bool STASH>
__launch_bounds__(256)
__global__ void sw_pass1(const float* __restrict__ in, const int* __restrict__ rep_idx,
                         const float* __restrict__ wsum, float* __restrict__ partial,
                         unsigned short* __restrict__ L1, unsigned short* __restrict__ L2,
                         unsigned short* __restrict__ S3) {
  const int bid = blockIdx.x;
  const int tid = threadIdx.x;

  // XCD swizzle: all 7 rb-blocks of channel c share bid mod 8 -> same XCD L2.
  const int c = (bid / 56) * 8 + (bid & 7);
  const int rb = (bid % 56) >> 3;
  if (c >= REPN) return;
  const int h0 = rb * 8;

  const int bq = tid / 14;             // 0..18; >=16 inactive
  const int tw = tid - bq * 14;        // 0..13
  const int w0 = tw * 4;
  const bool act = (bq < 16);

  float wv[45];  // block-uniform -> scalar loads
  #pragma unroll
  for (int j = 0; j < 45; ++j) wv[j] = wsum[c * 45 + j];

  float s1 = 0, q1 = 0, s2 = 0, q2 = 0, s3 = 0, q3 = 0;

  if (act) {
    const int src_c = rep_idx[c];
    const int ibaseA = (bq * CIN + src_c) * IMG;
    const int ibaseB = ((bq + 16) * CIN + src_c) * IMG;
    const int sbaseA = (bq * REPN + c) * IMG;
    const int sbaseB = ((bq + 16) * REPN + c) * IMG;

    const float ma = (tw >= 2) ? 1.f : 0.f;   // window col masks
    const float mb = (tw >= 1) ? 1.f : 0.f;
    const float mc = (tw <= 12) ? 1.f : 0.f;
    const float md = (tw <= 11) ? 1.f : 0.f;

    const int s_lo = (rb == 0) ? 6 : 0;       // r = h0-6+s in [0,56)
    const int s_hi = (rb == 6) ? 13 : 21;

    float a1A[8][4] = {}, a1B[8][4] = {};
    float a2A[3][4] = {}, a2B[3][4] = {};
    float a3A[3][4] = {}, a3B[3][4] = {};

    #pragma unroll
    for (int s = 0; s < 22; ++s) {
      if (s >= s_lo && s <= s_hi) {
        const int r = h0 - 6 + s;
        const int roff = r * HW + w0 - 8;
        // 10 unconditional loads up front -> one wait, 2x compute behind it
        float wA[20], wB[20];
        load_row20(wA, in, ibaseA + roff);
        load_row20(wB, in, ibaseB + roff);
        #pragma unroll
        for (int e = 0; e < 4; ++e)  { wA[e] *= ma; wB[e] *= ma; }
        #pragma unroll
        for (int e = 4; e < 8; ++e)  { wA[e] *= mb; wB[e] *= mb; }
        #pragma unroll
        for (int e = 12; e < 16; ++e) { wA[e] *= mc; wB[e] *= mc; }
        #pragma unroll
        for (int e = 16; e < 20; ++e) { wA[e] *= md; wB[e] *= md; }

        // lora1 (15x3): vertical tap t = s - lr; x col -> e = dw+kw+7
        #pragma unroll
        for (int lr = 0; lr < 8; ++lr) {
          const int t = s - lr;
          if (t >= 0 && t < 15) {
            #pragma unroll
            for (int kw = 0; kw < 3; ++kw) {
              const float wgt = wv[3 * t + kw];
              #pragma unroll
              for (int dw = 0; dw < 4; ++dw) {
                a1A[lr][dw] = fmaf(wA[dw + kw + 7], wgt, a1A[lr][dw]);
                a1B[lr][dw] = fmaf(wB[dw + kw + 7], wgt, a1B[lr][dw]);
              }
            }
          }
        }
        // lora2 (3x15) + small (3x3): kh = s - lr - 5
        #pragma unroll
        for (int lr = 0; lr < 8; ++lr) {
          const int kh = s - lr - 5;
          if (kh >= 0 && kh < 3) {
            #pragma unroll
            for (int T = 0; T < 15; ++T) {      // horiz tap -> e = dw+T+2
              const float wgt = wv[(T / 3) * 9 + kh * 3 + (T % 3)];
              #pragma unroll
              for (int dw = 0; dw < 4; ++dw) {
                a2A[lr % 3][dw] = fmaf(wA[dw + T + 2], wgt, a2A[lr % 3][dw]);
                a2B[lr % 3][dw] = fmaf(wB[dw + T + 2], wgt, a2B[lr % 3][dw]);
              }
            }
            #pragma unroll
            for (int kw = 0; kw < 3; ++kw) {
              const float wgt = wv[18 + kh * 3 + kw];
              #pragma unroll
              for (int dw = 0; dw < 4; ++dw) {
                a3A[lr % 3][dw] = fmaf(wA[dw + kw + 7], wgt, a3A[lr % 3][dw]);
                a3B[lr % 3][dw] = fmaf(wB[dw + kw + 7], wgt, a3B[lr % 3][dw]);
              }
            }
          }
        }
      }

      if (s >= 14) {               // fold1: lora1 row lr complete
        const int lr = s - 14;
        #pragma unroll
        for (int dw = 0; dw < 4; ++dw) {
          const float xA = a1A[lr][dw], xB = a1B[lr][dw];
          s1 += xA + xB; q1 = fmaf(xA, xA, q1); q1 = fmaf(xB, xB, q1);
        }
        if (STASH) {
          ushort4 tA, tB;
          tA.x = pack_bf16(a1A[lr][0]); tA.y = pack_bf16(a1A[lr][1]);
          tA.z = pack_bf16(a1A[lr][2]); tA.w = pack_bf16(a1A[lr][3]);
          tB.x = pack_bf16(a1B[lr][0]); tB.y = pack_bf16(a1B[lr][1]);
          tB.z = pack_bf16(a1B[lr][2]); tB.w = pack_bf16(a1B[lr][3]);
          const int ro = (h0 + lr) * HW + w0;
          *reinterpret_cast<ushort4*>(L1 + sbaseA + ro) = tA;
          *reinterpret_cast<ushort4*>(L1 + sbaseB + ro) = tB;
        }
      }
      if (s >= 7 && s <= 14) {     // fold2: lora2/small row lr complete
        const int lr = s - 7;
        if (STASH) {
          ushort4 t2A, t3A, t2B, t3B;
          t2A.x = pack_bf16(a2A[lr % 3][0]); t2A.y = pack_bf16(a2A[lr % 3][1]);
          t2A.z = pack_bf16(a2A[lr % 3][2]); t2A.w = pack_bf16(a2A[lr % 3][3]);
          t3A.x = pack_bf16(a3A[lr % 3][0]); t3A.y = pack_bf16(a3A[lr % 3][1]);
          t3A.z = pack_bf16(a3A[lr % 3][2]); t3A.w = pack_bf16(a3A[lr % 3][3]);
          t2B.x = pack_bf16(a2B[lr % 3][0]); t2B.y = pack_bf16(a2B[lr % 3][1]);
          t2B.z = pack_bf16(a2B[lr % 3][2]); t2B.w = pack_bf16(a2B[lr % 3][3]);
          t3B.x = pack_bf16(a3B[lr % 3][0]); t3B.y = pack_bf16(a3B[lr % 3][1]);
          t3B.z = pack_bf16(a3B[lr % 3][2]); t3B.w = pack_bf16(a3B[lr % 3][3]);
          const int ro = (h0 + lr) * HW + w0;
          *reinterpret_cast<ushort4*>(L2 + sbaseA + ro) = t2A;
          *reinterpret_cast<ushort4*>(S3 + sbaseA + ro) = t3A;
          *reinterpret_cast<ushort4*>(L2 + sbaseB + ro) = t2B;
          *reinterpret_cast<ushort4*>(S3 + sbaseB + ro) = t3B;
        }
        #pragma unroll
        for (int dw = 0; dw < 4; ++dw) {
          const float v2A = a2A[lr % 3][dw], v3A = a3A[lr % 3][dw];
          const float v2B = a2B[lr % 3][dw], v3B = a3B[lr % 3][dw];
          s2 += v2A + v2B; q2 = fmaf(v2A, v2A, q2); q2 = fmaf(v2B, v2B, q2);
          s3 += v3A + v3B; q3 = fmaf(v3A, v3A, q3); q3 = fmaf(v3B, v3B, q3);
          a2A[lr % 3][dw] = 0.f; a2B[lr % 3][dw] = 0.f;
          a3A[lr % 3][dw] = 0.f; a3B[lr % 3][dw] = 0.f;
        }
      }
    }
  }

  __shared__ float red[4][6];
  #pragma unroll
  for (int off = 32; off > 0; off >>= 1) {
    s1 += __shfl_down(s1, off); q1 += __shfl_down(q1, off);
    s2 += __shfl_down(s2, off); q2 += __shfl_down(q2, off);
    s3 += __shfl_down(s3, off); q3 += __shfl_down(q3, off);
  }
  const int lane = tid & 63, wid = tid >> 6;
  if (lane == 0) {
    red[wid][0] = s1; red[wid][1] = q1; red[wid][2] = s2;
    red[wid][3] = q2; red[wid][4] = s3; red[wid][5] = q3;
  }
  __syncthreads();
  if (tid < 6)
    partial[(c * 7 + rb) * 6 + tid] =
        red[0][tid] + red[1][tid] + red[2][tid] + red[3][tid];
}

// ---------- Fallback pass2: r4-exact recompute (only if ws too small) ----------
__launch_bounds__(448)
__global__ void sw_pass2r(const float* __restrict__ in, const int* __restrict__ rep_idx,
                          const int* __restrict__ ghost_idx, const float* __restrict__ wsum,
                          const float* __restrict__ stats2, float* __restrict__ out) {
  const int bid = blockIdx.x;
  const int tid = threadIdx.x;

  if (bid >= NCONV2R) {
    const int g = bid - NCONV2R;
    const int j = g >> 5, b = g & 31;
    const int src_c = ghost_idx[j];
    const float4* s = reinterpret_cast<const float4*>(in + (size_t)(b * CIN + src_c) * IMG);
    float4* d = reinterpret_cast<float4*>(out + ((size_t)(b * CIN) + REPN + j) * IMG);
    #pragma unroll 1
    for (int i = tid; i < 784; i += 448) d[i] = s[i];
    return;
  }

  const int c = (bid / 56) * 8 + (bid & 7);
  const int rb = (bid % 56) >> 3;
  if (c >= REPN) return;
  const int h0 = rb * 8;

  const int b = tid / 14;
  const int tw = tid - b * 14;
  const int w0 = tw * 4;
  const int src_c = rep_idx[c];
  const int ibase = (b * CIN + src_c) * IMG;

  float wv[45];
  #pragma unroll
  for (int j = 0; j < 45; ++j) wv[j] = wsum[c * 45 + j];

  const float A1 = stats2[c * 4 + 0], A2 = stats2[c * 4 + 1];
  const float A3 = stats2[c * 4 + 2], K_ = stats2[c * 4 + 3];

  const float ma = (tw >= 2) ? 1.f : 0.f;
  const float mb = (tw >= 1) ? 1.f : 0.f;
  const float mc = (tw <= 12) ? 1.f : 0.f;
  const float md = (tw <= 11) ? 1.f : 0.f;

  float acc1[8][4] = {};
  float acc2[3][4] = {};
  float acc3[3][4] = {};
  float stash[7][4];

  #pragma unroll
  for (int s = 0; s < 22; ++s) {
    const int r = h0 - 6 + s;
    if (r >= 0 && r < HW) {
      float win[20];
      load_row20(win, in, ibase + r * HW + w0 - 8);
      #pragma unroll
      for (int e = 0; e < 4; ++e) win[e] *= ma;
      #pragma unroll
      for (int e = 4; e < 8; ++e) win[e] *= mb;
      #pragma unroll
      for (int e = 12; e < 16; ++e) win[e] *= mc;
      #pragma unroll
      for (int e = 16; e < 20; ++e) win[e] *= md;

      #pragma unroll
      for (int lr = 0; lr < 8; ++lr) {
        const int t = s - lr;
        if (t >= 0 && t < 15) {
          #pragma unroll
          for (int kw = 0; kw < 3; ++kw) {
            const float wgt = wv[3 * t + kw];
            #pragma unroll
            for (int dw = 0; dw < 4; ++dw)
              acc1[lr][dw] = fmaf(win[dw + kw + 7], wgt, acc1[lr][dw]);
          }
        }
      }
      #pragma unroll
      for (int lr = 0; lr < 8; ++lr) {
        const int kh = s - lr - 5;
        if (kh >= 0 && kh < 3) {
          #pragma unroll
          for (int T = 0; T < 15; ++T) {
            const float wgt = wv[(T / 3) * 9 + kh * 3 + (T % 3)];
            #pragma unroll
            for (int dw = 0; dw < 4; ++dw)
              acc2[lr % 3][dw] = fmaf(win[dw + T + 2], wgt, acc2[lr % 3][dw]);
          }
          #pragma unroll
          for (int kw = 0; kw < 3; ++kw) {
            const float wgt = wv[18 + kh * 3 + kw];
            #pragma unroll
            for (int dw = 0; dw < 4; ++dw)
              acc3[lr % 3][dw] = fmaf(win[dw + kw + 7], wgt, acc3[lr % 3][dw]);
          }
        }
      }
    }

    if (s >= 14) {
      const int lr = s - 14;
      const int hh = h0 + lr;
      const float4 xv = *reinterpret_cast<const float4*>(in + ibase + hh * HW + w0);
      float4 o;
      o.x = fmaf(A1, acc1[lr][0], stash[lr % 7][0] + K_ + xv.x);
      o.y = fmaf(A1, acc1[lr][1], stash[lr % 7][1] + K_ + xv.y);
      o.z = fmaf(A1, acc1[lr][2], stash[lr % 7][2] + K_ + xv.z);
      o.w = fmaf(A1, acc1[lr][3], stash[lr % 7][3] + K_ + xv.w);
      *reinterpret_cast<float4*>(out + (size_t)(b * CIN + c) * IMG + hh * HW + w0) = o;
    }
    if (s >= 7 && s <= 14) {
      const int lr = s - 7;
      #pragma unroll
      for (int dw = 0; dw < 4; ++dw) {
        stash[lr % 7][dw] = fmaf(A2, acc2[lr % 3][dw], A3 * acc3[lr % 3][dw]);
        acc2[lr % 3][dw] = 0.f;
        acc3[lr % 3][dw] = 0.f;
      }
    }
  }
}

// ---------- Fast pass2: streaming normalize from bf16 stash ----------
__launch_bounds__(256)
__global__ void sw_norm(const float* __restrict__ in, const int* __restrict__ rep_idx,
                        const int* __restrict__ ghost_idx, const float* __restrict__ stats2,
                        const unsigned short* __restrict__ L1,
                        const unsigned short* __restrict__ L2,
                        const unsigned short* __restrict__ S3,
                        float* __restrict__ out) {
  const int bid = blockIdx.x;
  const int tid = threadIdx.x;
  if (bid >= 6272) {  // ghost copy
    const int g = bid - 6272;
    const int j = g >> 5, b = g & 31;
    const int src_c = ghost_idx[j];
    const float4* s = reinterpret_cast<const float4*>(in + (size_t)(b * CIN + src_c) * IMG);
    float4* d = reinterpret_cast<float4*>(out + ((size_t)(b * CIN) + REPN + j) * IMG);
    #pragma unroll 1
    for (int i = tid; i < 784; i += 256) d[i] = s[i];
    return;
  }
  const int c = bid >> 5, b = bid & 31;
  const float A1 = stats2[c * 4 + 0], A2 = stats2[c * 4 + 1];
  const float A3 = stats2[c * 4 + 2], K_ = stats2[c * 4 + 3];
  const int xb4 = (b * CIN + rep_idx[c]) * IMG / 4;
  const int ob4 = (b * CIN + c) * IMG / 4;
  const int sb4 = (b * REPN + c) * IMG / 4;
  const float4* xp = reinterpret_cast<const float4*>(in) + xb4;
  float4* op = reinterpret_cast<float4*>(out) + ob4;
  const ushort4* l1p = reinterpret_cast<const ushort4*>(L1) + sb4;
  const ushort4* l2p = reinterpret_cast<const ushort4*>(L2) + sb4;
  const ushort4* s3p = reinterpret_cast<const ushort4*>(S3) + sb4;
  #pragma unroll 1
  for (int g = tid; g < 784; g += 256) {
    const float4 x = xp[g];
    const ushort4 a = l1p[g], d2 = l2p[g], d3 = s3p[g];
    float4 y;
    y.x = fmaf(A1, __uint_as_float((unsigned)a.x << 16),
          fmaf(A2, __uint_as_float((unsigned)d2.x << 16),
          fmaf(A3, __uint_as_float((unsigned)d3.x << 16), K_ + x.x)));
    y.y = fmaf(A1, __uint_as_float((unsigned)a.y << 16),
          fmaf(A2, __uint_as_float((unsigned)d2.y << 16),
          fmaf(A3, __uint_as_float((unsigned)d3.y << 16), K_ + x.y)));
    y.z = fmaf(A1, __uint_as_float((unsigned)a.z << 16),
          fmaf(A2, __uint_as_float((unsigned)d2.z << 16),
          fmaf(A3, __uint_as_float((unsigned)d3.z << 16), K_ + x.z)));
    y.w = fmaf(A1, __uint_as_float((unsigned)a.w << 16),
          fmaf(A2, __uint_as_float((unsigned)d2.w << 16),
          fmaf(A3, __uint_as_float((unsigned)d3.w << 16), K_ + x.w)));
    op[g] = y;
  }
}

extern "C" __global__ void sw_prep(const float* __restrict__ w1, const float* __restrict__ w2,
                                   float* __restrict__ wsum) {
  int i = blockIdx.x * 256 + threadIdx.x;
  if (i < 8820) wsum[i] = w1[i] + w2[i];
}

extern "C" __global__ void sw_reduce(
    const float* __restrict__ partial,
    const float* __restrict__ g1, const float* __restrict__ b1,
    const float* __restrict__ g2, const float* __restrict__ b2,
    const float* __restrict__ g3, const float* __restrict__ b3,
    float* __restrict__ stats2) {
  const int c = blockIdx.x;
  const int tid = threadIdx.x;
  __shared__ float sm[6];
  if (tid < 6) {
    float s = 0;
    #pragma unroll
    for (int rb = 0; rb < 7; ++rb) s += partial[(c * 7 + rb) * 6 + tid];
    sm[tid] = s;
  }
  __syncthreads();
  if (tid == 0) {
    const float N = 100352.f;
    float m1 = sm[0] / N, v1 = sm[1] / N - m1 * m1;
    float m2 = sm[2] / N, v2 = sm[3] / N - m2 * m2;
    float m3 = sm[4] / N, v3 = sm[5] / N - m3 * m3;
    float A1 = g1[c] * rsqrtf(v1 + 1e-5f);
    float A2 = g2[c] * rsqrtf(v2 + 1e-5f);
    float A3 = g3[c] * rsqrtf(v3 + 1e-5f);
    float K = b1[c] + b2[c] + b3[c] - m1 * A1 - m2 * A2 - m3 * A3;
    stats2[c * 4 + 0] = A1; stats2[c * 4 + 1] = A2;
    stats2[c * 4 + 2] = A3; stats2[c * 4 + 3] = K;
  }
}

extern "C" void kernel_launch(void* const* d_in, const int* in_sizes, int n_in,
                              void* d_out, int out_size, void* d_ws, size_t ws_size,
                              hipStream_t stream) {
  const float* in  = (const float*)d_in[0];
  const float* w1  = (const float*)d_in[1];
  const float* w2  = (const float*)d_in[2];
  const float* g1  = (const float*)d_in[3];
  const float* b1  = (const float*)d_in[4];
  const float* g2  = (const float*)d_in[5];
  const float* b2  = (const float*)d_in[6];
  const float* g3  = (const float*)d_in[7];
  const float* b3  = (const float*)d_in[8];
  const int* ghost_idx = (const int*)d_in[9];
  const int* rep_idx   = (const int*)d_in[10];
  float* out = (float*)d_out;
  float* ws  = (float*)d_ws;

  float* wsum    = ws;          // 8820 floats
  float* stats2  = ws + 8832;   // 784 floats
  float* partial = ws + 9728;   // 1372*6 floats
  unsigned short* L1 = reinterpret_cast<unsigned short*>((char*)d_ws + (1u << 18));
  unsigned short* L2 = L1 + STASH_ELEMS;
  unsigned short* S3 = L2 + STASH_ELEMS;
  const size_t need = (1u << 18) + 3ull * STASH_ELEMS * sizeof(unsigned short);

  sw_prep<<<35, 256, 0, stream>>>(w1, w2, wsum);
  if (ws_size >= need) {
    sw_pass1<true><<<NCONV1, 256, 0, stream>>>(in, rep_idx, wsum, partial, L1, L2, S3);
    sw_reduce<<<196, 64, 0, stream>>>(partial, g1, b1, g2, b2, g3, b3, stats2);
    sw_norm<<<6272 + NGHOSTBLK, 256, 0, stream>>>(in, rep_idx, ghost_idx, stats2,
                                                  L1, L2, S3, out);
  } else {
    sw_pass1<false><<<NCONV1, 256, 0, stream>>>(in, rep_idx, wsum, partial, L1, L2, S3);
    sw_reduce<<<196, 64, 0, stream>>>(partial, g1, b1, g2, b2, g3, b3, stats2);
    sw_pass2r<<<NCONV2R + NGHOSTBLK, 448, 0, stream>>>(in, rep_idx, ghost_idx, wsum,
                                                       stats2, out);
  }
}